// Round 1
// baseline (95.305 us; speedup 1.0000x reference)
//
#include <hip/hip_runtime.h>
#include <math.h>

#define BATCH 256
#define DIMZ  64
#define NSAMP 32
#define JB    8   // j values per block (8 j x 32 s = 256 threads)

__global__ __launch_bounds__(256) void lpo_kl_kernel(
    const float* __restrict__ prior_mean,
    const float* __restrict__ prior_logvar,
    const float* __restrict__ post_mean,
    const float* __restrict__ post_logvar,
    const float* __restrict__ eps,
    float* __restrict__ out)
{
    constexpr float LOG_2PI = 1.8378770664093453f;
    constexpr float VAR_EPS = 1e-4f;
    constexpr float LOG2E   = 1.4426950408889634f;
    constexpr float LN2     = 0.6931471805599453f;
    constexpr float LOG_B   = 5.545177444479562f;   // ln(256)

    // SoA tables so the inner loop reads 4 i-entries per ds_read_b128
    __shared__ __align__(16) float m_s[BATCH];   // post_mean[i,d]
    __shared__ __align__(16) float a_s[BATCH];   // c1 * den  (c1/invn)
    __shared__ __align__(16) float v_s[BATCH];   // LOG2E / den
    __shared__ float sg_s[BATCH];                // exp(0.5*logvar) for z
    __shared__ float wred[4];

    const int tid = threadIdx.x;
    const int d   = blockIdx.x & (DIMZ - 1);
    const int j0  = (blockIdx.x >> 6) * JB;

    // Build the per-d posterior table: one entry per batch index i.
    {
        const int i = tid;
        float m   = post_mean[i * DIMZ + d];
        float lv  = post_logvar[i * DIMZ + d];
        float den = 2.0f * __expf(lv) + VAR_EPS;
        float c1n = -0.5f * LOG_2PI - 0.5f * lv;
        m_s[i]  = m;
        a_s[i]  = c1n * den;       // t2 = (a - sq) * v  ==  LOG2E*(c1 - sq/den)
        v_s[i]  = LOG2E / den;
        sg_s[i] = __expf(0.5f * lv);
    }
    __syncthreads();

    const int s  = tid & (NSAMP - 1);
    const int jj = tid >> 5;
    const int j  = j0 + jj;

    // reparameterized sample z_{j,d,s}
    const float z = m_s[j] + eps[(j * DIMZ + d) * NSAMP + s] * sg_s[j];

    // sum_i 2^{log2 p_i(z)}  -- no max-stabilization needed:
    //  upper bound: t2 <= ~2.2  -> sum <= ~1100 (no overflow)
    //  lower bound: diagonal i=j term has t2 >= ~-30 (no underflow-to-zero)
    float sum0 = 0.f, sum1 = 0.f, sum2 = 0.f, sum3 = 0.f;
    #pragma unroll 4
    for (int i = 0; i < BATCH; i += 4) {
        const float4 mv = *(const float4*)(m_s + i);
        const float4 av = *(const float4*)(a_s + i);
        const float4 iv = *(const float4*)(v_s + i);
        float d0 = z - mv.x; sum0 += __builtin_amdgcn_exp2f((av.x - d0 * d0) * iv.x);
        float d1 = z - mv.y; sum1 += __builtin_amdgcn_exp2f((av.y - d1 * d1) * iv.y);
        float d2 = z - mv.z; sum2 += __builtin_amdgcn_exp2f((av.z - d2 * d2) * iv.z);
        float d3 = z - mv.w; sum3 += __builtin_amdgcn_exp2f((av.w - d3 * d3) * iv.w);
    }
    const float sum = (sum0 + sum1) + (sum2 + sum3);

    // prior log-density at z (natural log domain, cheap: once per output)
    const float pm   = prior_mean[j * DIMZ + d];
    const float plv  = prior_logvar[j * DIMZ + d];
    const float pden = 2.0f * __expf(plv) + VAR_EPS;
    const float dz   = z - pm;
    const float logp_prior = -0.5f * LOG_2PI - 0.5f * plv - dz * dz / pden;

    // logsumexp_nat = ln2 * log2(sum); subtract ln(B); gap; mean over (j,s), sum over d
    const float lse_nat = LN2 * __builtin_amdgcn_logf(sum) - LOG_B;
    float contrib = (lse_nat - logp_prior) * (1.0f / (BATCH * NSAMP));

    // wave reduce (width 64), then cross-wave via LDS, one atomic per block
    for (int off = 32; off > 0; off >>= 1)
        contrib += __shfl_down(contrib, off);
    if ((tid & 63) == 0) wred[tid >> 6] = contrib;
    __syncthreads();
    if (tid == 0)
        atomicAdd(out, (wred[0] + wred[1]) + (wred[2] + wred[3]));
}

extern "C" void kernel_launch(void* const* d_in, const int* in_sizes, int n_in,
                              void* d_out, int out_size, void* d_ws, size_t ws_size,
                              hipStream_t stream) {
    const float* prior_mean   = (const float*)d_in[0];
    const float* prior_logvar = (const float*)d_in[1];
    const float* post_mean    = (const float*)d_in[2];
    const float* post_logvar  = (const float*)d_in[3];
    const float* eps          = (const float*)d_in[4];
    float* out = (float*)d_out;

    // harness poisons d_out with 0xAA before every timed launch
    hipMemsetAsync(out, 0, sizeof(float), stream);

    lpo_kl_kernel<<<dim3((BATCH / JB) * DIMZ), dim3(256), 0, stream>>>(
        prior_mean, prior_logvar, post_mean, post_logvar, eps, out);
}